// Round 7
// baseline (215.328 us; speedup 1.0000x reference)
//
#include <hip/hip_runtime.h>

#define PSZ 16
#define BATCH 32
#define IMGH 512
#define IMGW 512
#define CH 3
#define NPATCH 1024            // patches per image (32x32)
#define K_TOT 768
#define N_TOT 256
#define ROWSTRIDE (IMGW*CH)    // 1536 floats per image row
#define IMGSTRIDE (IMGH*IMGW*CH)

#define BM 64
#define BN 128
#define BK 64
#define KPAD 72                // LDS K-stride (bf16): 144B rows, 16B-aligned (72=8*9)
#define NKIT (K_TOT/BK)        // 12

typedef __bf16 bf16_t;
typedef bf16_t bf16x8 __attribute__((ext_vector_type(8)));
typedef float f32x4 __attribute__((ext_vector_type(4)));

// ---------------- prep: W[768][256] fp32 -> fragment-direct hi/lo bf16x8 arrays ----------
// Layout: frag index t = ((bcg*12 + kit)*2 + ks)*64 + lane, value[e] =
//   W[(kit*64 + ks*32 + (lane>>4)*8 + e)*256 + bcg*16 + (lane&15)]
// so a wave's B-fragment load is 64 lanes x 16B contiguous (1KB, perfectly coalesced).
__global__ void prep_w(const float* __restrict__ Wsrc,
                       bf16x8* __restrict__ wfh, bf16x8* __restrict__ wfl) {
    int t = blockIdx.x * 256 + threadIdx.x;      // 0..24575
    int lane = t & 63;
    int ks = (t >> 6) & 1;
    int rest = t >> 7;                           // 0..191
    int kit = rest % 12;
    int bcg = rest / 12;                         // 0..15
    int col = bcg * 16 + (lane & 15);
    int kbase = kit * 64 + ks * 32 + ((lane >> 4) << 3);
    bf16x8 h, l;
#pragma unroll
    for (int e = 0; e < 8; ++e) {
        float v = Wsrc[(size_t)(kbase + e) * N_TOT + col];
        bf16_t hh = (bf16_t)v;
        h[e] = hh;
        l[e] = (bf16_t)(v - (float)hh);
    }
    wfh[t] = h;
    wfl[t] = l;
}

// ---------------- cls row: out[b,0,:] = cls + pos ----------------
__global__ void cls_add(const float* __restrict__ cls, const float* __restrict__ pos,
                        float* __restrict__ out) {
    int i = blockIdx.x * 256 + threadIdx.x;   // 8192
    int b = i >> 8, h = i & 255;
    size_t o = (size_t)b * (NPATCH + 1) * N_TOT + h;
    out[o] = cls[i] + pos[o];
}

// ---------------- main: patchify + split-bf16 MFMA GEMM, A dbuf in LDS, B direct ----------
__global__ __launch_bounds__(256, 4)
void patch_gemm(const float* __restrict__ x,
                const bf16x8* __restrict__ wfh, const bf16x8* __restrict__ wfl,
                const float* __restrict__ bias, const float* __restrict__ pos,
                float* __restrict__ out) {
    __shared__ bf16_t Ah[2][BM * KPAD];
    __shared__ bf16_t Al[2][BM * KPAD];

    // chunked XCD swizzle: 1024 = 8 XCDs * 128; keeps the ntile-pair (shared A rows)
    // on the same XCD L2.
    const int bid = blockIdx.x;
    const int t = (bid & 7) * 128 + (bid >> 3);
    const int mtile = t >> 1;   // 0..511
    const int ntile = t & 1;    // 0..1

    const int tid = threadIdx.x;
    const int lane = tid & 63;
    const int wid = tid >> 6;
    const int wr = wid >> 1, wc = wid & 1;   // 2x2 wave grid; wave tile 32x64

    const int m0 = mtile * BM;
    const int n0 = ntile * BN;

    f32x4 acc[2][4] = {};

    const int l15 = lane & 15;
    const int kgrp = (lane >> 4) << 3;        // 0,8,16,24
    const int bcg0 = ntile * 8 + wc * 4;      // this wave's first 16-col group

    // A-staging geometry (constant per thread): 2 rows x 8 k-floats each
    const int rowb = tid >> 3;                // 0..31
    const int kl8 = (tid & 7) << 3;           // 0..56
    const float* srcbase[2];
#pragma unroll
    for (int i = 0; i < 2; ++i) {
        int row = rowb + 32 * i;
        int pm = m0 + row;
        int b = pm >> 10, pid = pm & 1023;
        int gr = pid >> 5, gc = pid & 31;
        srcbase[i] = x + (size_t)b * IMGSTRIDE + (gr * PSZ) * ROWSTRIDE + gc * (PSZ * CH);
    }

#define LOADA(KIT, P0, P1, P2, P3)                                        \
    {                                                                      \
        int d = (KIT) * BK + kl8;                                          \
        int prow = d / 48, poff = d % 48;                                  \
        const float* s0 = srcbase[0] + prow * ROWSTRIDE + poff;            \
        const float* s1 = srcbase[1] + prow * ROWSTRIDE + poff;            \
        P0 = *(const float4*)s0;  P1 = *(const float4*)(s0 + 4);           \
        P2 = *(const float4*)s1;  P3 = *(const float4*)(s1 + 4);           \
    }

#define CVTSTORE(BUF, P0, P1, P2, P3)                                      \
    {                                                                      \
        bf16x8 h, l;                                                       \
        h[0]=(bf16_t)P0.x; l[0]=(bf16_t)(P0.x-(float)h[0]);                \
        h[1]=(bf16_t)P0.y; l[1]=(bf16_t)(P0.y-(float)h[1]);                \
        h[2]=(bf16_t)P0.z; l[2]=(bf16_t)(P0.z-(float)h[2]);                \
        h[3]=(bf16_t)P0.w; l[3]=(bf16_t)(P0.w-(float)h[3]);                \
        h[4]=(bf16_t)P1.x; l[4]=(bf16_t)(P1.x-(float)h[4]);                \
        h[5]=(bf16_t)P1.y; l[5]=(bf16_t)(P1.y-(float)h[5]);                \
        h[6]=(bf16_t)P1.z; l[6]=(bf16_t)(P1.z-(float)h[6]);                \
        h[7]=(bf16_t)P1.w; l[7]=(bf16_t)(P1.w-(float)h[7]);                \
        *reinterpret_cast<bf16x8*>(&Ah[BUF][rowb * KPAD + kl8]) = h;       \
        *reinterpret_cast<bf16x8*>(&Al[BUF][rowb * KPAD + kl8]) = l;       \
        h[0]=(bf16_t)P2.x; l[0]=(bf16_t)(P2.x-(float)h[0]);                \
        h[1]=(bf16_t)P2.y; l[1]=(bf16_t)(P2.y-(float)h[1]);                \
        h[2]=(bf16_t)P2.z; l[2]=(bf16_t)(P2.z-(float)h[2]);                \
        h[3]=(bf16_t)P2.w; l[3]=(bf16_t)(P2.w-(float)h[3]);                \
        h[4]=(bf16_t)P3.x; l[4]=(bf16_t)(P3.x-(float)h[4]);                \
        h[5]=(bf16_t)P3.y; l[5]=(bf16_t)(P3.y-(float)h[5]);                \
        h[6]=(bf16_t)P3.z; l[6]=(bf16_t)(P3.z-(float)h[6]);                \
        h[7]=(bf16_t)P3.w; l[7]=(bf16_t)(P3.w-(float)h[7]);                \
        *reinterpret_cast<bf16x8*>(&Ah[BUF][(rowb + 32) * KPAD + kl8]) = h;\
        *reinterpret_cast<bf16x8*>(&Al[BUF][(rowb + 32) * KPAD + kl8]) = l;\
    }

    // ---- prologue: stage k-tile 0 ----
    float4 p0, p1, p2, p3;
    LOADA(0, p0, p1, p2, p3);
    CVTSTORE(0, p0, p1, p2, p3);
    __syncthreads();

#pragma unroll 2
    for (int kit = 0; kit < NKIT; ++kit) {
        const int cur = kit & 1;
        // issue next A-tile loads early (latency hides under this iter's compute)
        if (kit < NKIT - 1) LOADA(kit + 1, p0, p1, p2, p3);

#pragma unroll
        for (int ks = 0; ks < 2; ++ks) {
            // B fragments straight from global (L2-resident, coalesced 1KB/wave)
            bf16x8 bfh[4], bfl[4];
#pragma unroll
            for (int bc = 0; bc < 4; ++bc) {
                int idx = (((bcg0 + bc) * 12 + kit) * 2 + ks) * 64 + lane;
                bfh[bc] = wfh[idx];
                bfl[bc] = wfl[idx];
            }
            const int kb = ks * 32 + kgrp;
            bf16x8 afh[2], afl[2];
#pragma unroll
            for (int ar = 0; ar < 2; ++ar) {
                int o = (wr * 32 + ar * 16 + l15) * KPAD + kb;
                afh[ar] = *reinterpret_cast<const bf16x8*>(&Ah[cur][o]);
                afl[ar] = *reinterpret_cast<const bf16x8*>(&Al[cur][o]);
            }
#pragma unroll
            for (int ar = 0; ar < 2; ++ar)
#pragma unroll
                for (int bc = 0; bc < 4; ++bc) {
                    acc[ar][bc] = __builtin_amdgcn_mfma_f32_16x16x32_bf16(afh[ar], bfh[bc], acc[ar][bc], 0, 0, 0);
                    acc[ar][bc] = __builtin_amdgcn_mfma_f32_16x16x32_bf16(afh[ar], bfl[bc], acc[ar][bc], 0, 0, 0);
                    acc[ar][bc] = __builtin_amdgcn_mfma_f32_16x16x32_bf16(afl[ar], bfh[bc], acc[ar][bc], 0, 0, 0);
                }
        }

        if (kit < NKIT - 1) CVTSTORE(cur ^ 1, p0, p1, p2, p3);
        __syncthreads();
    }

    // ---- epilogue: C/D layout col=lane&15, row=(lane>>4)*4+j ----
    const int colbase = n0 + wc * 64;
    float bvals[4];
#pragma unroll
    for (int bc = 0; bc < 4; ++bc) bvals[bc] = bias[colbase + bc * 16 + l15];

#pragma unroll
    for (int ar = 0; ar < 2; ++ar) {
        int rbase = m0 + wr * 32 + ar * 16 + ((lane >> 4) << 2);
#pragma unroll
        for (int j = 0; j < 4; ++j) {
            int pm = rbase + j;
            int b = pm >> 10, p = pm & 1023;
            size_t orow = (size_t)(b * (NPATCH + 1) + 1 + p) * N_TOT;
#pragma unroll
            for (int bc = 0; bc < 4; ++bc) {
                int col = colbase + bc * 16 + l15;
                out[orow + col] = acc[ar][bc][j] + bvals[bc] + pos[orow + col];
            }
        }
    }
#undef LOADA
#undef CVTSTORE
}

extern "C" void kernel_launch(void* const* d_in, const int* in_sizes, int n_in,
                              void* d_out, int out_size, void* d_ws, size_t ws_size,
                              hipStream_t stream) {
    const float* x    = (const float*)d_in[0];
    const float* W    = (const float*)d_in[1];
    const float* bias = (const float*)d_in[2];
    const float* cls  = (const float*)d_in[3];
    const float* pos  = (const float*)d_in[4];
    float* out = (float*)d_out;

    bf16x8* wfh = (bf16x8*)d_ws;
    bf16x8* wfl = wfh + 24576;

    prep_w<<<96, 256, 0, stream>>>(W, wfh, wfl);
    cls_add<<<32, 256, 0, stream>>>(cls, pos, out);
    patch_gemm<<<1024, 256, 0, stream>>>(x, wfh, wfl, bias, pos, out);
}

// Round 9
// 210.146 us; speedup vs baseline: 1.0247x; 1.0247x over previous
//
#include <hip/hip_runtime.h>

#define PSZ 16
#define BATCH 32
#define IMGH 512
#define IMGW 512
#define CH 3
#define NPATCH 1024            // patches per image (32x32)
#define K_TOT 768
#define N_TOT 256
#define ROWSTRIDE (IMGW*CH)    // 1536 floats per image row
#define IMGSTRIDE (IMGH*IMGW*CH)

#define BM 64
#define BN 128
#define BK 64
#define KPAD 72                // LDS K-stride (bf16): 144B rows, 16B-aligned (72=8*9)
#define NKIT (K_TOT/BK)        // 12

typedef __bf16 bf16_t;
typedef bf16_t bf16x8 __attribute__((ext_vector_type(8)));
typedef float f32x4 __attribute__((ext_vector_type(4)));

// ---------------- prep: W[768][256] fp32 -> fragment-direct hi/lo bf16x8 arrays ----------
// Layout: frag index t = ((bcg*12 + kit)*2 + ks)*64 + lane, value[e] =
//   W[(kit*64 + ks*32 + (lane>>4)*8 + e)*256 + bcg*16 + (lane&15)]
// so a wave's B-fragment load is 64 lanes x 16B contiguous (1KB, perfectly coalesced).
__global__ void prep_w(const float* __restrict__ Wsrc,
                       bf16x8* __restrict__ wfh, bf16x8* __restrict__ wfl) {
    int t = blockIdx.x * 256 + threadIdx.x;      // 0..24575
    int lane = t & 63;
    int ks = (t >> 6) & 1;
    int rest = t >> 7;                           // 0..191
    int kit = rest % 12;
    int bcg = rest / 12;                         // 0..15
    int col = bcg * 16 + (lane & 15);
    int kbase = kit * 64 + ks * 32 + ((lane >> 4) << 3);
    bf16x8 h, l;
#pragma unroll
    for (int e = 0; e < 8; ++e) {
        float v = Wsrc[(size_t)(kbase + e) * N_TOT + col];
        bf16_t hh = (bf16_t)v;
        h[e] = hh;
        l[e] = (bf16_t)(v - (float)hh);
    }
    wfh[t] = h;
    wfl[t] = l;
}

// ---------------- cls row: out[b,0,:] = cls + pos ----------------
__global__ void cls_add(const float* __restrict__ cls, const float* __restrict__ pos,
                        float* __restrict__ out) {
    int i = blockIdx.x * 256 + threadIdx.x;   // 8192
    int b = i >> 8, h = i & 255;
    size_t o = (size_t)b * (NPATCH + 1) * N_TOT + h;
    out[o] = cls[i] + pos[o];
}

// ---------------- main: patchify + split-bf16 MFMA GEMM, A dbuf in LDS, B direct ----------
// launch_bounds(256,2): R2's (256,4) capped VGPR at 64 and serialized all memory
// latency; 2 waves/EU min -> up to 256 VGPRs, letting the whole kit's loads batch.
__global__ __launch_bounds__(256, 2)
void patch_gemm(const float* __restrict__ x,
                const bf16x8* __restrict__ wfh, const bf16x8* __restrict__ wfl,
                const float* __restrict__ bias, const float* __restrict__ pos,
                float* __restrict__ out) {
    __shared__ bf16_t Ah[2][BM * KPAD];
    __shared__ bf16_t Al[2][BM * KPAD];

    // chunked XCD swizzle: 1024 = 8 XCDs * 128; keeps the ntile-pair (shared A rows)
    // on the same XCD L2.
    const int bid = blockIdx.x;
    const int t = (bid & 7) * 128 + (bid >> 3);
    const int mtile = t >> 1;   // 0..511
    const int ntile = t & 1;    // 0..1

    const int tid = threadIdx.x;
    const int lane = tid & 63;
    const int wid = tid >> 6;
    const int wr = wid >> 1, wc = wid & 1;   // 2x2 wave grid; wave tile 32x64

    const int m0 = mtile * BM;
    const int n0 = ntile * BN;

    f32x4 acc[2][4] = {};

    const int l15 = lane & 15;
    const int kgrp = (lane >> 4) << 3;        // 0,8,16,24
    const int bcg0 = ntile * 8 + wc * 4;      // this wave's first 16-col group

    // A-staging geometry (constant per thread): 2 rows x 8 k-floats each
    const int rowb = tid >> 3;                // 0..31
    const int kl8 = (tid & 7) << 3;           // 0..56
    const float* srcbase[2];
#pragma unroll
    for (int i = 0; i < 2; ++i) {
        int row = rowb + 32 * i;
        int pm = m0 + row;
        int b = pm >> 10, pid = pm & 1023;
        int gr = pid >> 5, gc = pid & 31;
        srcbase[i] = x + (size_t)b * IMGSTRIDE + (gr * PSZ) * ROWSTRIDE + gc * (PSZ * CH);
    }

#define LOADA(KIT, P0, P1, P2, P3)                                        \
    {                                                                      \
        int d = (KIT) * BK + kl8;                                          \
        int prow = d / 48, poff = d % 48;                                  \
        const float* s0 = srcbase[0] + prow * ROWSTRIDE + poff;            \
        const float* s1 = srcbase[1] + prow * ROWSTRIDE + poff;            \
        P0 = *(const float4*)s0;  P1 = *(const float4*)(s0 + 4);           \
        P2 = *(const float4*)s1;  P3 = *(const float4*)(s1 + 4);           \
    }

#define CVTSTORE(BUF, P0, P1, P2, P3)                                      \
    {                                                                      \
        bf16x8 h, l;                                                       \
        h[0]=(bf16_t)P0.x; l[0]=(bf16_t)(P0.x-(float)h[0]);                \
        h[1]=(bf16_t)P0.y; l[1]=(bf16_t)(P0.y-(float)h[1]);                \
        h[2]=(bf16_t)P0.z; l[2]=(bf16_t)(P0.z-(float)h[2]);                \
        h[3]=(bf16_t)P0.w; l[3]=(bf16_t)(P0.w-(float)h[3]);                \
        h[4]=(bf16_t)P1.x; l[4]=(bf16_t)(P1.x-(float)h[4]);                \
        h[5]=(bf16_t)P1.y; l[5]=(bf16_t)(P1.y-(float)h[5]);                \
        h[6]=(bf16_t)P1.z; l[6]=(bf16_t)(P1.z-(float)h[6]);                \
        h[7]=(bf16_t)P1.w; l[7]=(bf16_t)(P1.w-(float)h[7]);                \
        *reinterpret_cast<bf16x8*>(&Ah[BUF][rowb * KPAD + kl8]) = h;       \
        *reinterpret_cast<bf16x8*>(&Al[BUF][rowb * KPAD + kl8]) = l;       \
        h[0]=(bf16_t)P2.x; l[0]=(bf16_t)(P2.x-(float)h[0]);                \
        h[1]=(bf16_t)P2.y; l[1]=(bf16_t)(P2.y-(float)h[1]);                \
        h[2]=(bf16_t)P2.z; l[2]=(bf16_t)(P2.z-(float)h[2]);                \
        h[3]=(bf16_t)P2.w; l[3]=(bf16_t)(P2.w-(float)h[3]);                \
        h[4]=(bf16_t)P3.x; l[4]=(bf16_t)(P3.x-(float)h[4]);                \
        h[5]=(bf16_t)P3.y; l[5]=(bf16_t)(P3.y-(float)h[5]);                \
        h[6]=(bf16_t)P3.z; l[6]=(bf16_t)(P3.z-(float)h[6]);                \
        h[7]=(bf16_t)P3.w; l[7]=(bf16_t)(P3.w-(float)h[7]);                \
        *reinterpret_cast<bf16x8*>(&Ah[BUF][(rowb + 32) * KPAD + kl8]) = h;\
        *reinterpret_cast<bf16x8*>(&Al[BUF][(rowb + 32) * KPAD + kl8]) = l;\
    }

    // ---- prologue: stage k-tile 0 ----
    float4 p0, p1, p2, p3;
    LOADA(0, p0, p1, p2, p3);
    CVTSTORE(0, p0, p1, p2, p3);
    __syncthreads();

#pragma unroll 2
    for (int kit = 0; kit < NKIT; ++kit) {
        const int cur = kit & 1;
        // issue next A-tile loads early (latency hides under this iter's compute)
        if (kit < NKIT - 1) LOADA(kit + 1, p0, p1, p2, p3);

        // hoist ALL B fragments for this kit: 16 coalesced loads, one vmcnt batch
        bf16x8 bfh[2][4], bfl[2][4];
#pragma unroll
        for (int ks = 0; ks < 2; ++ks)
#pragma unroll
            for (int bc = 0; bc < 4; ++bc) {
                int idx = (((bcg0 + bc) * 12 + kit) * 2 + ks) * 64 + lane;
                bfh[ks][bc] = wfh[idx];
                bfl[ks][bc] = wfl[idx];
            }

        // ---- ks = 0 ----
        {
            const int kb = kgrp;
            bf16x8 afh[2], afl[2];
#pragma unroll
            for (int ar = 0; ar < 2; ++ar) {
                int o = (wr * 32 + ar * 16 + l15) * KPAD + kb;
                afh[ar] = *reinterpret_cast<const bf16x8*>(&Ah[cur][o]);
                afl[ar] = *reinterpret_cast<const bf16x8*>(&Al[cur][o]);
            }
#pragma unroll
            for (int ar = 0; ar < 2; ++ar)
#pragma unroll
                for (int bc = 0; bc < 4; ++bc) {
                    acc[ar][bc] = __builtin_amdgcn_mfma_f32_16x16x32_bf16(afh[ar], bfh[0][bc], acc[ar][bc], 0, 0, 0);
                    acc[ar][bc] = __builtin_amdgcn_mfma_f32_16x16x32_bf16(afh[ar], bfl[0][bc], acc[ar][bc], 0, 0, 0);
                    acc[ar][bc] = __builtin_amdgcn_mfma_f32_16x16x32_bf16(afl[ar], bfh[0][bc], acc[ar][bc], 0, 0, 0);
                }
        }

        // convert+store next A tile mid-iteration: frees staged regs, and the
        // ds_writes drain while ks=1 MFMAs run (barrier then waits on less)
        if (kit < NKIT - 1) CVTSTORE(cur ^ 1, p0, p1, p2, p3);

        // ---- ks = 1 ----
        {
            const int kb = 32 + kgrp;
            bf16x8 afh[2], afl[2];
#pragma unroll
            for (int ar = 0; ar < 2; ++ar) {
                int o = (wr * 32 + ar * 16 + l15) * KPAD + kb;
                afh[ar] = *reinterpret_cast<const bf16x8*>(&Ah[cur][o]);
                afl[ar] = *reinterpret_cast<const bf16x8*>(&Al[cur][o]);
            }
#pragma unroll
            for (int ar = 0; ar < 2; ++ar)
#pragma unroll
                for (int bc = 0; bc < 4; ++bc) {
                    acc[ar][bc] = __builtin_amdgcn_mfma_f32_16x16x32_bf16(afh[ar], bfh[1][bc], acc[ar][bc], 0, 0, 0);
                    acc[ar][bc] = __builtin_amdgcn_mfma_f32_16x16x32_bf16(afh[ar], bfl[1][bc], acc[ar][bc], 0, 0, 0);
                    acc[ar][bc] = __builtin_amdgcn_mfma_f32_16x16x32_bf16(afl[ar], bfh[1][bc], acc[ar][bc], 0, 0, 0);
                }
        }

        __syncthreads();
    }

    // ---- epilogue: C/D layout col=lane&15, row=(lane>>4)*4+j ----
    const int colbase = n0 + wc * 64;
    float bvals[4];
#pragma unroll
    for (int bc = 0; bc < 4; ++bc) bvals[bc] = bias[colbase + bc * 16 + l15];

#pragma unroll
    for (int ar = 0; ar < 2; ++ar) {
        int rbase = m0 + wr * 32 + ar * 16 + ((lane >> 4) << 2);
#pragma unroll
        for (int j = 0; j < 4; ++j) {
            int pm = rbase + j;
            int b = pm >> 10, p = pm & 1023;
            size_t orow = (size_t)(b * (NPATCH + 1) + 1 + p) * N_TOT;
#pragma unroll
            for (int bc = 0; bc < 4; ++bc) {
                int col = colbase + bc * 16 + l15;
                out[orow + col] = acc[ar][bc][j] + bvals[bc] + pos[orow + col];
            }
        }
    }
#undef LOADA
#undef CVTSTORE
}

extern "C" void kernel_launch(void* const* d_in, const int* in_sizes, int n_in,
                              void* d_out, int out_size, void* d_ws, size_t ws_size,
                              hipStream_t stream) {
    const float* x    = (const float*)d_in[0];
    const float* W    = (const float*)d_in[1];
    const float* bias = (const float*)d_in[2];
    const float* cls  = (const float*)d_in[3];
    const float* pos  = (const float*)d_in[4];
    float* out = (float*)d_out;

    bf16x8* wfh = (bf16x8*)d_ws;
    bf16x8* wfl = wfh + 24576;

    prep_w<<<96, 256, 0, stream>>>(W, wfh, wfl);
    cls_add<<<32, 256, 0, stream>>>(cls, pos, out);
    patch_gemm<<<1024, 256, 0, stream>>>(x, wfh, wfl, bias, pos, out);
}